// Round 3
// baseline (1368.066 us; speedup 1.0000x reference)
//
#include <hip/hip_runtime.h>
#include <math.h>

typedef short s16x8 __attribute__((ext_vector_type(8)));
typedef short s16x4 __attribute__((ext_vector_type(4)));
typedef float f32x4 __attribute__((ext_vector_type(4)));

constexpr int NB = 32, CI = 64, IH = 128, IW = 128;
constexpr int PLANE = IH * IW;                 // 16384
constexpr int CHW = CI * PLANE;                // 1<<20
constexpr long long HALF = (long long)NB * CHW;
constexpr float EPS = 1e-5f;

// ws byte offsets
constexpr size_t WS_ZERO  = 256;               // 256 B of zeros (staging OOB redirect)
constexpr size_t WS_WCONV = 512;               // ushort[2][25][64][64]   (409,600 B)
constexpr size_t WS_WGATE = 512 + 409600;      // ushort[192][128]        (49,152 B)
constexpr size_t WS_XN = (size_t)1 << 20;      // x NHWC bf16 (64 MB)
constexpr size_t WS_HN = ((size_t)1 << 20) + ((size_t)64 << 20); // h NHWC bf16

constexpr int EXT_STRIDE = 268;                // ushorts; 536 B: 8B-aligned, odd word stride

__device__ __forceinline__ ushort f2bf(float f) {
    unsigned u = __float_as_uint(f);
    return (ushort)((u + 0x7fffu + ((u >> 16) & 1u)) >> 16);
}
__device__ __forceinline__ float bf2f(ushort h) { return __uint_as_float(((unsigned)h) << 16); }
__device__ __forceinline__ float sigf(float z) { return 1.0f / (1.0f + __expf(-z)); }
__device__ __forceinline__ float tanhfast(float z) { return 1.0f - 2.0f / (__expf(2.0f * z) + 1.0f); }
#define MFMA(a, b, c) __builtin_amdgcn_mfma_f32_16x16x32_bf16(a, b, c, 0, 0, 0)

// ---- pre-pass: weights -> bf16, MFMA-friendly layouts ----
// wconv[cv][tap][co][ci], wgate[n][k] (k = 0..63 x-ci, 64..127 h-ci)
// identity-tap trick: exc center tap gets +I so conv_exc(h) = h + exc directly.
__global__ __launch_bounds__(256) void k_prep_w(
    const float* __restrict__ w_xg, const float* __restrict__ w_hg,
    const float* __restrict__ w_exc, const float* __restrict__ w_inh,
    ushort* __restrict__ wconv, ushort* __restrict__ wgate)
{
    int idx = blockIdx.x * 256 + threadIdx.x;
    if (idx < 204800) {
        int cv = idx / 102400;
        int rem = idx - cv * 102400;
        int t = rem >> 12;
        int rem2 = rem & 4095;
        int co = rem2 >> 6, ci = rem2 & 63;
        const float* src = cv ? w_inh : w_exc;
        float v = src[(co * 64 + ci) * 25 + t];
        if (cv == 0 && t == 12 && co == ci) v += 1.0f;   // identity tap: h + exc
        wconv[idx] = f2bf(v);
    } else if (idx < 204800 + 24576) {
        int g = idx - 204800;
        int n = g >> 7, k = g & 127;
        float v = (k < 64) ? w_xg[n * 64 + k] : w_hg[n * 64 + (k - 64)];
        wgate[g] = f2bf(v);
    }
}

// ---- pre-pass: x,h NCHW fp32 -> NHWC bf16 (vectorized: float4 in, uint4 out) ----
__global__ __launch_bounds__(256) void k_nhwc(const float* __restrict__ x,
    const float* __restrict__ h, ushort* __restrict__ xn, ushort* __restrict__ hn)
{
    __shared__ float t[64][129];
    int bid = blockIdx.x;
    const float* src; ushort* dst;
    if (bid < 4096) { src = x; dst = xn; } else { src = h; dst = hn; bid -= 4096; }
    int b = bid >> 7, y = bid & 127;
    const float* s0 = src + (size_t)b * CHW + y * IW;
    for (int e = threadIdx.x; e < 2048; e += 256) {
        int ci = e >> 5, x4 = (e & 31) << 2;
        float4 v = *(const float4*)(s0 + (size_t)ci * PLANE + x4);
        t[ci][x4] = v.x; t[ci][x4 + 1] = v.y; t[ci][x4 + 2] = v.z; t[ci][x4 + 3] = v.w;
    }
    __syncthreads();
    ushort* d0 = dst + ((size_t)(b * IH + y)) * IW * 64;
    for (int e = threadIdx.x; e < 1024; e += 256) {
        int xx = e >> 3, cig = (e & 7) << 3;
        uint4 pk;
        pk.x = (unsigned)f2bf(t[cig + 0][xx]) | ((unsigned)f2bf(t[cig + 1][xx]) << 16);
        pk.y = (unsigned)f2bf(t[cig + 2][xx]) | ((unsigned)f2bf(t[cig + 3][xx]) << 16);
        pk.z = (unsigned)f2bf(t[cig + 4][xx]) | ((unsigned)f2bf(t[cig + 5][xx]) << 16);
        pk.w = (unsigned)f2bf(t[cig + 6][xx]) | ((unsigned)f2bf(t[cig + 7][xx]) << 16);
        *(uint4*)(d0 + ((size_t)xx << 6) + cig) = pk;
    }
}

// ---- main fused cell: 2 rows/block, 512 threads ----
// Phases: [stage0 issue | gates-o | S | conv0 | S | stage1 issue | gates-if | S |
//          conv1 | S | ext-write | S | epilogue]  (5 barriers; staging hidden under gates)
__global__ __launch_bounds__(512, 3) void k_cell(
    const ushort* __restrict__ xn, const ushort* __restrict__ hn,
    const float* __restrict__ c,
    const ushort* __restrict__ wconv, const ushort* __restrict__ wgate,
    const float* __restrict__ b_xg, const float* __restrict__ b_hg,
    const float* __restrict__ b_exc, const float* __restrict__ b_inh,
    const ushort* __restrict__ zpad,
    float* __restrict__ out, float* __restrict__ red)
{
    // union: halo [6][132][32] ushort (50,688 B) | ext [2][64][EXT_STRIDE] ushort (68,608 B)
    __shared__ ushort sm[2 * 64 * EXT_STRIDE];
    __shared__ float reds[8], redq[8];
    const int tid = threadIdx.x;
    const int w = tid >> 6, lane = tid & 63;
    const int n16 = lane & 15, quad = lane >> 4;
    // XCD-bijective swizzle: 2048 blocks = 8 XCDs x 256; each XCD gets contiguous chunk
    const int bid = blockIdx.x;
    const int swz = (bid & 7) * 256 + (bid >> 3);
    const int b = swz >> 6, y0 = (swz & 63) * 2;

    // conv wave split: cv = exc/inh, pg = 64-px group (ro = row, ph = col-half)
    const int cv = w >> 2, pg = w & 3;
    const int ro = pg >> 1, ph = (pg & 1) * 64;
    // gate/epilogue split: wave w owns px w*32..+31
    const int prow = w >> 2, pc0 = (w & 3) * 32;
    const ushort* xr = xn + ((size_t)(b * IH + y0 + prow) * IW + pc0) * 64;
    const ushort* hr = hn + ((size_t)(b * IH + y0 + prow) * IW + pc0) * 64;

    // ---- staging issue (no wait; branch-free via zero-pad redirect) ----
    auto stage = [&](int ci0) {
#pragma unroll
        for (int k = 0; k < 7; ++k) {
            int e = k * 512 + tid;
            if (e < 3168) {
                int dy = e / 528;
                int rem = e - dy * 528;
                int xi = rem >> 2, cg = rem & 3;
                int yy = y0 + dy - 2, gx = xi - 2;
                bool ok = ((unsigned)yy < 128u) & ((unsigned)gx < 128u);
                const ushort* srcp = ok
                    ? (hn + (((size_t)(b * IH + yy)) * IW + gx) * 64 + ci0 + cg * 8)
                    : zpad;
                __builtin_amdgcn_global_load_lds(
                    (const __attribute__((address_space(1))) unsigned int*)srcp,
                    (__attribute__((address_space(3))) unsigned int*)(sm + (size_t)e * 8),
                    16, 0, 0);
            }
        }
    };

    f32x4 accC[4][4];
    // ---- conv over one ci-half, B double-buffered one tap ahead ----
    auto conv_ch = [&](int ci0) {
        const ushort* wcb = wconv + cv * 102400 + ci0 + quad * 8;
        s16x8 bA[4], bB[4];
#pragma unroll
        for (int ct = 0; ct < 4; ++ct)
            bA[ct] = *(const s16x8*)(wcb + (ct * 16 + n16) * 64);
        auto body = [&](int tap, s16x8* bc, s16x8* bn, bool pf) {
            const int dy = tap / 5, dx = tap - dy * 5;
            s16x8 a[4];
#pragma unroll
            for (int mt = 0; mt < 4; ++mt)
                a[mt] = *(const s16x8*)(sm + ((ro + dy) * 132 + ph + mt * 16 + n16 + dx) * 32 + quad * 8);
            if (pf) {
#pragma unroll
                for (int ct = 0; ct < 4; ++ct)
                    bn[ct] = *(const s16x8*)(wcb + (tap + 1) * 4096 + (ct * 16 + n16) * 64);
            }
#pragma unroll
            for (int ct = 0; ct < 4; ++ct)
#pragma unroll
                for (int mt = 0; mt < 4; ++mt)
                    accC[mt][ct] = MFMA(a[mt], bc[ct], accC[mt][ct]);
        };
#pragma unroll
        for (int tp = 0; tp < 12; ++tp) {
            body(2 * tp, bA, bB, true);
            body(2 * tp + 1, bB, bA, true);
        }
        body(24, bA, bB, false);
    };

    // ================= phase 1: issue stage ch0, hide under o-gate GEMM =========
    stage(0);
    {   // o-gate (n-tiles 8..11): reg-local, straight to global
        f32x4 accO[2][4];
#pragma unroll
        for (int m = 0; m < 2; ++m)
#pragma unroll
            for (int g = 0; g < 4; ++g) accO[m][g] = (f32x4){0.f, 0.f, 0.f, 0.f};
#pragma unroll
        for (int kb = 0; kb < 4; ++kb) {
            const ushort* ab = (kb >= 2) ? hr : xr;
            const int ko = (kb & 1) * 32;
            s16x8 a0 = *(const s16x8*)(ab + n16 * 64 + ko + quad * 8);
            s16x8 a1 = *(const s16x8*)(ab + (16 + n16) * 64 + ko + quad * 8);
#pragma unroll
            for (int g = 0; g < 4; ++g) {
                s16x8 bb = *(const s16x8*)(wgate + ((g + 8) * 16 + n16) * 128 + kb * 32 + quad * 8);
                accO[0][g] = MFMA(a0, bb, accO[0][g]);
                accO[1][g] = MFMA(a1, bb, accO[1][g]);
            }
        }
#pragma unroll
        for (int ct = 0; ct < 4; ++ct) {
            const int co = ct * 16 + n16;
            const float bo = b_xg[128 + co] + b_hg[128 + co];
            float* obase = out + (size_t)b * CHW + (size_t)co * PLANE + (size_t)(y0 + prow) * IW + pc0;
#pragma unroll
            for (int mt = 0; mt < 2; ++mt) {
                f32x4 og;
#pragma unroll
                for (int r = 0; r < 4; ++r) og[r] = sigf(accO[mt][ct][r] + bo);
                *(f32x4*)(obase + mt * 16 + quad * 4) = og;
            }
        }
    }
#pragma unroll
    for (int m = 0; m < 4; ++m)
#pragma unroll
        for (int n = 0; n < 4; ++n) accC[m][n] = (f32x4){0.f, 0.f, 0.f, 0.f};
    __syncthreads();                                   // stage ch0 complete

    // ================= phase 2: conv ch0 =================
    conv_ch(0);
    __syncthreads();                                   // conv ch0 reads done

    // ================= phase 3: issue stage ch1, hide under i/f-gate GEMM =======
    stage(32);
    unsigned packIF[2][4][4];
    {   // i,f gates (n-tiles 0..7) -> packed bf16 pairs in regs
        f32x4 accIF[2][8];
#pragma unroll
        for (int m = 0; m < 2; ++m)
#pragma unroll
            for (int g = 0; g < 8; ++g) accIF[m][g] = (f32x4){0.f, 0.f, 0.f, 0.f};
#pragma unroll
        for (int kb = 0; kb < 4; ++kb) {
            const ushort* ab = (kb >= 2) ? hr : xr;
            const int ko = (kb & 1) * 32;
            s16x8 a0 = *(const s16x8*)(ab + n16 * 64 + ko + quad * 8);
            s16x8 a1 = *(const s16x8*)(ab + (16 + n16) * 64 + ko + quad * 8);
#pragma unroll
            for (int g = 0; g < 8; ++g) {
                s16x8 bb = *(const s16x8*)(wgate + (g * 16 + n16) * 128 + kb * 32 + quad * 8);
                accIF[0][g] = MFMA(a0, bb, accIF[0][g]);
                accIF[1][g] = MFMA(a1, bb, accIF[1][g]);
            }
        }
#pragma unroll
        for (int ct = 0; ct < 4; ++ct) {
            const int co = ct * 16 + n16;
            const float bi = b_xg[co] + b_hg[co];
            const float bff = b_xg[64 + co] + b_hg[64 + co];
#pragma unroll
            for (int mt = 0; mt < 2; ++mt)
#pragma unroll
                for (int r = 0; r < 4; ++r) {
                    float ig = sigf(accIF[mt][ct][r] + bi);
                    float fg = sigf(accIF[mt][ct + 4][r] + bff);
                    packIF[mt][ct][r] = (unsigned)f2bf(ig) | ((unsigned)f2bf(fg) << 16);
                }
        }
    }
    __syncthreads();                                   // stage ch1 complete

    // ================= phase 4: conv ch1 =================
    conv_ch(32);
    __syncthreads();                                   // halo dead -> ext writable

    // ---- write conv results (bias added) to ext[cv][co][px] as packed b64 ----
#pragma unroll
    for (int ct = 0; ct < 4; ++ct) {
        const int co = ct * 16 + n16;
        const float bias = (cv ? b_inh : b_exc)[co];
        ushort* eb = sm + (cv * 64 + co) * EXT_STRIDE;
#pragma unroll
        for (int mt = 0; mt < 4; ++mt) {
            int pxb = ro * 128 + ph + mt * 16 + quad * 4;
            unsigned lo = (unsigned)f2bf(accC[mt][ct][0] + bias)
                        | ((unsigned)f2bf(accC[mt][ct][1] + bias) << 16);
            unsigned hi = (unsigned)f2bf(accC[mt][ct][2] + bias)
                        | ((unsigned)f2bf(accC[mt][ct][3] + bias) << 16);
            uint2 pk; pk.x = lo; pk.y = hi;
            *(uint2*)(eb + pxb) = pk;
        }
    }
    __syncthreads();                                   // ext visible

    // ---- epilogue in MFMA fragment layout, fully vectorized (float4) ----
    // identity-tap: ext[0] already holds (h + exc + b_exc); hor = sig(-inh)*ext0
    float lsum = 0.f, lsq = 0.f;
    {
        const size_t rowoff = (size_t)b * CHW + (size_t)(y0 + prow) * IW + pc0;
        const float* cb = c + rowoff;
        float* ob = out + HALF + rowoff;
        const int pxb0 = prow * 128 + pc0;
#pragma unroll
        for (int mt = 0; mt < 2; ++mt)
#pragma unroll
            for (int ct = 0; ct < 4; ++ct) {
                const int co = ct * 16 + n16;
                const int po = mt * 16 + quad * 4;
                s16x4 e4 = *(const s16x4*)(sm + co * EXT_STRIDE + pxb0 + po);
                s16x4 i4 = *(const s16x4*)(sm + (64 + co) * EXT_STRIDE + pxb0 + po);
                f32x4 cold = *(const f32x4*)(cb + (size_t)co * PLANE + po);
                f32x4 cn;
#pragma unroll
                for (int r = 0; r < 4; ++r) {
                    float ev = bf2f((ushort)e4[r]);
                    float iv = bf2f((ushort)i4[r]);
                    unsigned pk = packIF[mt][ct][r];
                    float ig = bf2f((ushort)(pk & 0xffffu));
                    float fg = bf2f((ushort)(pk >> 16));
                    float hor = sigf(-iv) * ev;
                    cn[r] = fg * cold[r] + ig * hor;
                    lsum += cn[r]; lsq += cn[r] * cn[r];
                }
                *(f32x4*)(ob + (size_t)co * PLANE + po) = cn;
            }
    }
#pragma unroll
    for (int off = 32; off > 0; off >>= 1) {
        lsum += __shfl_down(lsum, off, 64);
        lsq  += __shfl_down(lsq, off, 64);
    }
    if (lane == 0) { reds[w] = lsum; redq[w] = lsq; }
    __syncthreads();
    if (tid == 0) {
        float s = 0.f, q = 0.f;
#pragma unroll
        for (int i = 0; i < 8; ++i) { s += reds[i]; q += redq[i]; }
        atomicAdd(&red[2 * b], s);
        atomicAdd(&red[2 * b + 1], q);
    }
}

// ---- LayerNorm + tanh + o-gate multiply ----
__global__ __launch_bounds__(256) void k_norm(float* __restrict__ out, const float* __restrict__ red)
{
    const float invN = 1.0f / (float)CHW;
    size_t idx = ((size_t)blockIdx.x * 256 + threadIdx.x) * 4;
    int b = (int)(idx >> 20);
    float s = red[2 * b], q = red[2 * b + 1];
    float mean = s * invN;
    float var = q * invN - mean * mean;
    float r = rsqrtf(var + EPS);
    float4 o = *(const float4*)(out + idx);
    float4 cn = *(const float4*)(out + HALF + idx);
    float4 hnv;
    hnv.x = o.x * tanhfast((cn.x - mean) * r);
    hnv.y = o.y * tanhfast((cn.y - mean) * r);
    hnv.z = o.z * tanhfast((cn.z - mean) * r);
    hnv.w = o.w * tanhfast((cn.w - mean) * r);
    *(float4*)(out + idx) = hnv;
}

extern "C" void kernel_launch(void* const* d_in, const int* in_sizes, int n_in,
                              void* d_out, int out_size, void* d_ws, size_t ws_size,
                              hipStream_t stream) {
    const float* x     = (const float*)d_in[0];
    const float* h     = (const float*)d_in[1];
    const float* c     = (const float*)d_in[2];
    const float* w_xg  = (const float*)d_in[3];
    const float* b_xg  = (const float*)d_in[4];
    const float* w_hg  = (const float*)d_in[5];
    const float* b_hg  = (const float*)d_in[6];
    const float* w_exc = (const float*)d_in[7];
    const float* b_exc = (const float*)d_in[8];
    const float* w_inh = (const float*)d_in[9];
    const float* b_inh = (const float*)d_in[10];
    float* out = (float*)d_out;
    char* wsb = (char*)d_ws;
    float* red = (float*)wsb;
    const ushort* zpad = (const ushort*)(wsb + WS_ZERO);
    ushort* wconv = (ushort*)(wsb + WS_WCONV);
    ushort* wgate = (ushort*)(wsb + WS_WGATE);
    ushort* xnh = (ushort*)(wsb + WS_XN);
    ushort* hnh = (ushort*)(wsb + WS_HN);

    hipMemsetAsync(wsb, 0, 512, stream);   // red accumulators + zero-pad buffer
    k_prep_w<<<896, 256, 0, stream>>>(w_xg, w_hg, w_exc, w_inh, wconv, wgate);
    k_nhwc<<<8192, 256, 0, stream>>>(x, h, xnh, hnh);
    k_cell<<<2048, 512, 0, stream>>>(xnh, hnh, c, wconv, wgate,
                                     b_xg, b_hg, b_exc, b_inh, zpad, out, red);
    k_norm<<<32768, 256, 0, stream>>>(out, red);
}

// Round 5
// 1127.061 us; speedup vs baseline: 1.2138x; 1.2138x over previous
//
#include <hip/hip_runtime.h>
#include <math.h>

typedef short s16x8 __attribute__((ext_vector_type(8)));
typedef short s16x4 __attribute__((ext_vector_type(4)));
typedef float f32x4 __attribute__((ext_vector_type(4)));

constexpr int NB = 32, CI = 64, IH = 128, IW = 128;
constexpr int PLANE = IH * IW;                 // 16384
constexpr int CHW = CI * PLANE;                // 1<<20
constexpr long long HALF = (long long)NB * CHW;
constexpr float EPS = 1e-5f;

// ws byte offsets
constexpr size_t WS_ZERO  = 256;               // 256 B of zeros (staging OOB redirect)
constexpr size_t WS_WCONV = 512;               // ushort[2][25][64][64]   (409,600 B)
constexpr size_t WS_WGATE = 512 + 409600;      // ushort[192][128]        (49,152 B)
constexpr size_t WS_XN = (size_t)1 << 20;      // x NHWC bf16 (64 MB)
constexpr size_t WS_HN = ((size_t)1 << 20) + ((size_t)64 << 20); // h NHWC bf16

constexpr int EXT_STRIDE = 268;                // ushorts; 536 B: 8B-aligned, odd word stride

__device__ __forceinline__ ushort f2bf(float f) {
    unsigned u = __float_as_uint(f);
    return (ushort)((u + 0x7fffu + ((u >> 16) & 1u)) >> 16);
}
__device__ __forceinline__ float bf2f(ushort h) { return __uint_as_float(((unsigned)h) << 16); }
__device__ __forceinline__ float sigf(float z) { return 1.0f / (1.0f + __expf(-z)); }
__device__ __forceinline__ float tanhfast(float z) { return 1.0f - 2.0f / (__expf(2.0f * z) + 1.0f); }
#define MFMA(a, b, c) __builtin_amdgcn_mfma_f32_16x16x32_bf16(a, b, c, 0, 0, 0)

// ---- pre-pass: weights -> bf16, MFMA-friendly layouts ----
// wconv[cv][tap][co][ci], wgate[n][k] (k = 0..63 x-ci, 64..127 h-ci)
// identity-tap trick: exc center tap gets +I so conv_exc(h) = h + exc directly.
__global__ __launch_bounds__(256) void k_prep_w(
    const float* __restrict__ w_xg, const float* __restrict__ w_hg,
    const float* __restrict__ w_exc, const float* __restrict__ w_inh,
    ushort* __restrict__ wconv, ushort* __restrict__ wgate)
{
    int idx = blockIdx.x * 256 + threadIdx.x;
    if (idx < 204800) {
        int cv = idx / 102400;
        int rem = idx - cv * 102400;
        int t = rem >> 12;
        int rem2 = rem & 4095;
        int co = rem2 >> 6, ci = rem2 & 63;
        const float* src = cv ? w_inh : w_exc;
        float v = src[(co * 64 + ci) * 25 + t];
        if (cv == 0 && t == 12 && co == ci) v += 1.0f;   // identity tap: h + exc
        wconv[idx] = f2bf(v);
    } else if (idx < 204800 + 24576) {
        int g = idx - 204800;
        int n = g >> 7, k = g & 127;
        float v = (k < 64) ? w_xg[n * 64 + k] : w_hg[n * 64 + (k - 64)];
        wgate[g] = f2bf(v);
    }
}

// ---- pre-pass: x,h NCHW fp32 -> NHWC bf16 (nt loads; temporal stores -> L3) ----
__global__ __launch_bounds__(256) void k_nhwc(const float* __restrict__ x,
    const float* __restrict__ h, ushort* __restrict__ xn, ushort* __restrict__ hn)
{
    __shared__ float t[64][129];
    int bid = blockIdx.x;
    const float* src; ushort* dst;
    if (bid < 4096) { src = x; dst = xn; } else { src = h; dst = hn; bid -= 4096; }
    int b = bid >> 7, y = bid & 127;
    const float* s0 = src + (size_t)b * CHW + y * IW;
    for (int e = threadIdx.x; e < 2048; e += 256) {
        int ci = e >> 5, x4 = (e & 31) << 2;
        f32x4 v = __builtin_nontemporal_load((const f32x4*)(s0 + (size_t)ci * PLANE + x4));
        t[ci][x4] = v[0]; t[ci][x4 + 1] = v[1]; t[ci][x4 + 2] = v[2]; t[ci][x4 + 3] = v[3];
    }
    __syncthreads();
    ushort* d0 = dst + ((size_t)(b * IH + y)) * IW * 64;
    for (int e = threadIdx.x; e < 1024; e += 256) {
        int xx = e >> 3, cig = (e & 7) << 3;
        uint4 pk;
        pk.x = (unsigned)f2bf(t[cig + 0][xx]) | ((unsigned)f2bf(t[cig + 1][xx]) << 16);
        pk.y = (unsigned)f2bf(t[cig + 2][xx]) | ((unsigned)f2bf(t[cig + 3][xx]) << 16);
        pk.z = (unsigned)f2bf(t[cig + 4][xx]) | ((unsigned)f2bf(t[cig + 5][xx]) << 16);
        pk.w = (unsigned)f2bf(t[cig + 6][xx]) | ((unsigned)f2bf(t[cig + 7][xx]) << 16);
        *(uint4*)(d0 + ((size_t)xx << 6) + cig) = pk;
    }
}

// ---- main fused cell: 2 rows/block, 512 threads (R2 phase order) ----
// Phases: [stage0 | S | conv0 | S | stage1 | S | conv1 | S | ext-write |
//          gates o,i,f (reg-local) | S | epilogue]
__global__ __launch_bounds__(512, 4) void k_cell(
    const ushort* __restrict__ xn, const ushort* __restrict__ hn,
    const float* __restrict__ c,
    const ushort* __restrict__ wconv, const ushort* __restrict__ wgate,
    const float* __restrict__ b_xg, const float* __restrict__ b_hg,
    const float* __restrict__ b_exc, const float* __restrict__ b_inh,
    const ushort* __restrict__ zpad,
    float* __restrict__ out, float* __restrict__ red)
{
    // union: halo [6][132][32] ushort (50,688 B) | ext [2][64][EXT_STRIDE] ushort (68,608 B)
    __shared__ ushort sm[2 * 64 * EXT_STRIDE];
    __shared__ float reds[8], redq[8];
    const int tid = threadIdx.x;
    const int w = tid >> 6, lane = tid & 63;
    const int n16 = lane & 15, quad = lane >> 4;
    // XCD-bijective swizzle: 2048 blocks = 8 XCDs x 256 contiguous each
    const int bid = blockIdx.x;
    const int swz = (bid & 7) * 256 + (bid >> 3);
    const int b = swz >> 6, y0 = (swz & 63) * 2;

    // conv wave split: cv = exc/inh, pg = 64-px group (ro = row, ph = col-half)
    const int cv = w >> 2, pg = w & 3;
    const int ro = pg >> 1, ph = (pg & 1) * 64;
    // gate/epilogue split: wave w owns px w*32..+31
    const int prow = w >> 2, pc0 = (w & 3) * 32;
    const ushort* xr = xn + ((size_t)(b * IH + y0 + prow) * IW + pc0) * 64;
    const ushort* hr = hn + ((size_t)(b * IH + y0 + prow) * IW + pc0) * 64;

    f32x4 accC[4][4];
#pragma unroll
    for (int m = 0; m < 4; ++m)
#pragma unroll
        for (int n = 0; n < 4; ++n) accC[m][n] = (f32x4){0.f, 0.f, 0.f, 0.f};

#pragma unroll 1
    for (int ch = 0; ch < 2; ++ch) {
        const int ci0 = ch * 32;
        if (ch) __syncthreads();                       // ch0 halo reads done
        // stage 6 halo rows x 132 x 32ci as [dy][xi][ci] bf16, branch-free
        for (int k = 0; k < 7; ++k) {
            int e = k * 512 + tid;
            if (e < 3168) {
                int dy = e / 528;
                int rem = e - dy * 528;
                int xi = rem >> 2, cg = rem & 3;
                int yy = y0 + dy - 2, gx = xi - 2;
                bool ok = ((unsigned)yy < 128u) & ((unsigned)gx < 128u);
                const ushort* srcp = ok
                    ? (hn + (((size_t)(b * IH + yy)) * IW + gx) * 64 + ci0 + cg * 8)
                    : zpad;
                __builtin_amdgcn_global_load_lds(
                    (const __attribute__((address_space(1))) unsigned int*)srcp,
                    (__attribute__((address_space(3))) unsigned int*)(sm + (size_t)e * 8),
                    16, 0, 0);
            }
        }
        __syncthreads();
        const ushort* wcb = wconv + cv * 102400 + ci0 + quad * 8;
#pragma unroll
        for (int dy = 0; dy < 5; ++dy)
#pragma unroll
            for (int dx = 0; dx < 5; ++dx) {
                const int tap = dy * 5 + dx;
                s16x8 a[4];
#pragma unroll
                for (int mt = 0; mt < 4; ++mt)
                    a[mt] = *(const s16x8*)(sm + ((ro + dy) * 132 + ph + mt * 16 + n16 + dx) * 32 + quad * 8);
#pragma unroll
                for (int ct = 0; ct < 4; ++ct) {
                    s16x8 bb = *(const s16x8*)(wcb + tap * 4096 + (ct * 16 + n16) * 64);
#pragma unroll
                    for (int mt = 0; mt < 4; ++mt)
                        accC[mt][ct] = MFMA(a[mt], bb, accC[mt][ct]);
                }
            }
    }
    __syncthreads();                                   // halo dead -> ext writable

    // ---- write conv results (bias added) to ext[cv][co][px] as packed b64 ----
#pragma unroll
    for (int ct = 0; ct < 4; ++ct) {
        const int co = ct * 16 + n16;
        const float bias = (cv ? b_inh : b_exc)[co];
        ushort* eb = sm + (cv * 64 + co) * EXT_STRIDE;
#pragma unroll
        for (int mt = 0; mt < 4; ++mt) {
            int pxb = ro * 128 + ph + mt * 16 + quad * 4;
            unsigned lo = (unsigned)f2bf(accC[mt][ct][0] + bias)
                        | ((unsigned)f2bf(accC[mt][ct][1] + bias) << 16);
            unsigned hi = (unsigned)f2bf(accC[mt][ct][2] + bias)
                        | ((unsigned)f2bf(accC[mt][ct][3] + bias) << 16);
            uint2 pk; pk.x = lo; pk.y = hi;
            *(uint2*)(eb + pxb) = pk;
        }
    }

    // ---- gates GEMM (A direct from global), three low-pressure passes ----
    unsigned packI[2][4][2], packF[2][4][2];
    {   // pass 1: o-gate (n-tiles 8..11) -> nt float4 store now, free regs
        f32x4 accO[2][4];
#pragma unroll
        for (int m = 0; m < 2; ++m)
#pragma unroll
            for (int g = 0; g < 4; ++g) accO[m][g] = (f32x4){0.f, 0.f, 0.f, 0.f};
#pragma unroll
        for (int kb = 0; kb < 4; ++kb) {
            const ushort* ab = (kb >= 2) ? hr : xr;
            const int ko = (kb & 1) * 32;
            s16x8 a0 = *(const s16x8*)(ab + n16 * 64 + ko + quad * 8);
            s16x8 a1 = *(const s16x8*)(ab + (16 + n16) * 64 + ko + quad * 8);
#pragma unroll
            for (int g = 0; g < 4; ++g) {
                s16x8 bb = *(const s16x8*)(wgate + ((g + 8) * 16 + n16) * 128 + kb * 32 + quad * 8);
                accO[0][g] = MFMA(a0, bb, accO[0][g]);
                accO[1][g] = MFMA(a1, bb, accO[1][g]);
            }
        }
#pragma unroll
        for (int ct = 0; ct < 4; ++ct) {
            const int co = ct * 16 + n16;
            const float bo = b_xg[128 + co] + b_hg[128 + co];
            float* obase = out + (size_t)b * CHW + (size_t)co * PLANE + (size_t)(y0 + prow) * IW + pc0;
#pragma unroll
            for (int mt = 0; mt < 2; ++mt) {
                f32x4 og;
#pragma unroll
                for (int r = 0; r < 4; ++r) og[r] = sigf(accO[mt][ct][r] + bo);
                __builtin_nontemporal_store(og, (f32x4*)(obase + mt * 16 + quad * 4));
            }
        }
    }
    {   // pass 2: i-gate (n-tiles 0..3) -> packed bf16 pairs (r-pairs)
        f32x4 accI[2][4];
#pragma unroll
        for (int m = 0; m < 2; ++m)
#pragma unroll
            for (int g = 0; g < 4; ++g) accI[m][g] = (f32x4){0.f, 0.f, 0.f, 0.f};
#pragma unroll
        for (int kb = 0; kb < 4; ++kb) {
            const ushort* ab = (kb >= 2) ? hr : xr;
            const int ko = (kb & 1) * 32;
            s16x8 a0 = *(const s16x8*)(ab + n16 * 64 + ko + quad * 8);
            s16x8 a1 = *(const s16x8*)(ab + (16 + n16) * 64 + ko + quad * 8);
#pragma unroll
            for (int g = 0; g < 4; ++g) {
                s16x8 bb = *(const s16x8*)(wgate + (g * 16 + n16) * 128 + kb * 32 + quad * 8);
                accI[0][g] = MFMA(a0, bb, accI[0][g]);
                accI[1][g] = MFMA(a1, bb, accI[1][g]);
            }
        }
#pragma unroll
        for (int ct = 0; ct < 4; ++ct) {
            const int co = ct * 16 + n16;
            const float bi = b_xg[co] + b_hg[co];
#pragma unroll
            for (int mt = 0; mt < 2; ++mt)
#pragma unroll
                for (int rp = 0; rp < 2; ++rp) {
                    float g0 = sigf(accI[mt][ct][2 * rp] + bi);
                    float g1 = sigf(accI[mt][ct][2 * rp + 1] + bi);
                    packI[mt][ct][rp] = (unsigned)f2bf(g0) | ((unsigned)f2bf(g1) << 16);
                }
        }
    }
    {   // pass 3: f-gate (n-tiles 4..7) -> packed bf16 pairs (r-pairs)
        f32x4 accF[2][4];
#pragma unroll
        for (int m = 0; m < 2; ++m)
#pragma unroll
            for (int g = 0; g < 4; ++g) accF[m][g] = (f32x4){0.f, 0.f, 0.f, 0.f};
#pragma unroll
        for (int kb = 0; kb < 4; ++kb) {
            const ushort* ab = (kb >= 2) ? hr : xr;
            const int ko = (kb & 1) * 32;
            s16x8 a0 = *(const s16x8*)(ab + n16 * 64 + ko + quad * 8);
            s16x8 a1 = *(const s16x8*)(ab + (16 + n16) * 64 + ko + quad * 8);
#pragma unroll
            for (int g = 0; g < 4; ++g) {
                s16x8 bb = *(const s16x8*)(wgate + ((g + 4) * 16 + n16) * 128 + kb * 32 + quad * 8);
                accF[0][g] = MFMA(a0, bb, accF[0][g]);
                accF[1][g] = MFMA(a1, bb, accF[1][g]);
            }
        }
#pragma unroll
        for (int ct = 0; ct < 4; ++ct) {
            const int co = ct * 16 + n16;
            const float bff = b_xg[64 + co] + b_hg[64 + co];
#pragma unroll
            for (int mt = 0; mt < 2; ++mt)
#pragma unroll
                for (int rp = 0; rp < 2; ++rp) {
                    float g0 = sigf(accF[mt][ct][2 * rp] + bff);
                    float g1 = sigf(accF[mt][ct][2 * rp + 1] + bff);
                    packF[mt][ct][rp] = (unsigned)f2bf(g0) | ((unsigned)f2bf(g1) << 16);
                }
        }
    }
    __syncthreads();                                   // ext visible

    // ---- epilogue in MFMA fragment layout, nt streaming for c and c_next ----
    // identity-tap: ext[0] already holds (h + exc + b_exc); hor = sig(-inh)*ext0
    float lsum = 0.f, lsq = 0.f;
    {
        const size_t rowoff = (size_t)b * CHW + (size_t)(y0 + prow) * IW + pc0;
        const float* cb = c + rowoff;
        float* ob = out + HALF + rowoff;
        const int pxb0 = prow * 128 + pc0;
#pragma unroll
        for (int mt = 0; mt < 2; ++mt)
#pragma unroll
            for (int ct = 0; ct < 4; ++ct) {
                const int co = ct * 16 + n16;
                const int po = mt * 16 + quad * 4;
                s16x4 e4 = *(const s16x4*)(sm + co * EXT_STRIDE + pxb0 + po);
                s16x4 i4 = *(const s16x4*)(sm + (64 + co) * EXT_STRIDE + pxb0 + po);
                f32x4 cold = __builtin_nontemporal_load((const f32x4*)(cb + (size_t)co * PLANE + po));
                f32x4 cn;
#pragma unroll
                for (int r = 0; r < 4; ++r) {
                    float ev = bf2f((ushort)e4[r]);
                    float iv = bf2f((ushort)i4[r]);
                    unsigned pi = packI[mt][ct][r >> 1];
                    unsigned pf = packF[mt][ct][r >> 1];
                    float ig = bf2f((ushort)((pi >> ((r & 1) * 16)) & 0xffffu));
                    float fg = bf2f((ushort)((pf >> ((r & 1) * 16)) & 0xffffu));
                    float hor = sigf(-iv) * ev;
                    cn[r] = fg * cold[r] + ig * hor;
                    lsum += cn[r]; lsq += cn[r] * cn[r];
                }
                __builtin_nontemporal_store(cn, (f32x4*)(ob + (size_t)co * PLANE + po));
            }
    }
#pragma unroll
    for (int off = 32; off > 0; off >>= 1) {
        lsum += __shfl_down(lsum, off, 64);
        lsq  += __shfl_down(lsq, off, 64);
    }
    if (lane == 0) { reds[w] = lsum; redq[w] = lsq; }
    __syncthreads();
    if (tid == 0) {
        float s = 0.f, q = 0.f;
#pragma unroll
        for (int i = 0; i < 8; ++i) { s += reds[i]; q += redq[i]; }
        atomicAdd(&red[2 * b], s);
        atomicAdd(&red[2 * b + 1], q);
    }
}

// ---- LayerNorm + tanh + o-gate multiply (fully streaming: nt in, nt out) ----
__global__ __launch_bounds__(256) void k_norm(float* __restrict__ out, const float* __restrict__ red)
{
    const float invN = 1.0f / (float)CHW;
    size_t idx = ((size_t)blockIdx.x * 256 + threadIdx.x) * 4;
    int b = (int)(idx >> 20);
    float s = red[2 * b], q = red[2 * b + 1];
    float mean = s * invN;
    float var = q * invN - mean * mean;
    float r = rsqrtf(var + EPS);
    f32x4 o = __builtin_nontemporal_load((const f32x4*)(out + idx));
    f32x4 cn = __builtin_nontemporal_load((const f32x4*)(out + HALF + idx));
    f32x4 hnv;
    hnv[0] = o[0] * tanhfast((cn[0] - mean) * r);
    hnv[1] = o[1] * tanhfast((cn[1] - mean) * r);
    hnv[2] = o[2] * tanhfast((cn[2] - mean) * r);
    hnv[3] = o[3] * tanhfast((cn[3] - mean) * r);
    __builtin_nontemporal_store(hnv, (f32x4*)(out + idx));
}

extern "C" void kernel_launch(void* const* d_in, const int* in_sizes, int n_in,
                              void* d_out, int out_size, void* d_ws, size_t ws_size,
                              hipStream_t stream) {
    const float* x     = (const float*)d_in[0];
    const float* h     = (const float*)d_in[1];
    const float* c     = (const float*)d_in[2];
    const float* w_xg  = (const float*)d_in[3];
    const float* b_xg  = (const float*)d_in[4];
    const float* w_hg  = (const float*)d_in[5];
    const float* b_hg  = (const float*)d_in[6];
    const float* w_exc = (const float*)d_in[7];
    const float* b_exc = (const float*)d_in[8];
    const float* w_inh = (const float*)d_in[9];
    const float* b_inh = (const float*)d_in[10];
    float* out = (float*)d_out;
    char* wsb = (char*)d_ws;
    float* red = (float*)wsb;
    const ushort* zpad = (const ushort*)(wsb + WS_ZERO);
    ushort* wconv = (ushort*)(wsb + WS_WCONV);
    ushort* wgate = (ushort*)(wsb + WS_WGATE);
    ushort* xnh = (ushort*)(wsb + WS_XN);
    ushort* hnh = (ushort*)(wsb + WS_HN);

    hipMemsetAsync(wsb, 0, 512, stream);   // red accumulators + zero-pad buffer
    k_prep_w<<<896, 256, 0, stream>>>(w_xg, w_hg, w_exc, w_inh, wconv, wgate);
    k_nhwc<<<8192, 256, 0, stream>>>(x, h, xnh, hnh);
    k_cell<<<2048, 512, 0, stream>>>(xnh, hnh, c, wconv, wgate,
                                     b_xg, b_hg, b_exc, b_inh, zpad, out, red);
    k_norm<<<32768, 256, 0, stream>>>(out, red);
}